// Round 1
// baseline (6369.773 us; speedup 1.0000x reference)
//
#include <hip/hip_runtime.h>

#define M_DIM 4096
#define K_DIM 4096
#define N_DIM 32768
#define TOPK  64

typedef __attribute__((ext_vector_type(8))) _Float16 half8;
typedef __attribute__((ext_vector_type(4))) _Float16 half4;
typedef __attribute__((ext_vector_type(4))) float    f32x4;

#define GLDS(gp, lp) __builtin_amdgcn_global_load_lds( \
    (const __attribute__((address_space(1))) void*)(gp), \
    (__attribute__((address_space(3))) void*)(lp), 16, 0, 0)

// ---------------- split: fp32 -> fp16 hi + fp16 lo*4096 ----------------
__launch_bounds__(256)
__global__ void split_kernel(const float4* __restrict__ src, half4* __restrict__ hi,
                             half4* __restrict__ lo, int n4) {
  int i = blockIdx.x * blockDim.x + threadIdx.x;
  int stride = gridDim.x * blockDim.x;
  for (; i < n4; i += stride) {
    float4 x = src[i];
    half4 h, l;
    float xs[4] = {x.x, x.y, x.z, x.w};
#pragma unroll
    for (int e = 0; e < 4; ++e) {
      _Float16 hh = (_Float16)xs[e];
      h[e] = hh;
      l[e] = (_Float16)((xs[e] - (float)hh) * 4096.0f);  // exact residual, pow2 scale
    }
    hi[i] = h;
    lo[i] = l;
  }
}

// ---------------- encode GEMM: a1 = x @ W^T + b_enc (split fp16, 3 products) ------
// m97 structure: 128x128 tile, BK=32, 4 waves of 64x64, 16x16x32 f16 MFMA,
// global_load_lds width 16, XOR chunk swizzle for conflict-free ds_read_b128.
__launch_bounds__(256)
__global__ void gemm_enc(const _Float16* __restrict__ xhi, const _Float16* __restrict__ xlo,
                         const _Float16* __restrict__ whi, const _Float16* __restrict__ wlo,
                         const float* __restrict__ b_enc, float* __restrict__ a1)
{
  __shared__ alignas(16) _Float16 lA[128 * 32];
  __shared__ alignas(16) _Float16 lB[128 * 32];

  const int tid  = threadIdx.x;
  const int lane = tid & 63;
  const int wave = tid >> 6;
  const int wm = wave & 1, wn = wave >> 1;

  // window swizzle: 32 windows of (32 m-tiles x 8 n-tiles) so concurrent blocks
  // reuse all of A (64 MB, L3-resident) while streaming B once.
  const int bid = blockIdx.x;
  const int window = bid >> 8;
  const int within = bid & 255;
  const int m0 = (within & 31) << 7;
  const int n0 = (((window << 3) | (within >> 5))) << 7;

  const int srow = tid >> 2;   // staging row (+64 for second round)
  const int sch  = tid & 3;    // 16B chunk within 64B row

  const int fm = lane & 15, fq = lane >> 4;
  const int swz = (fm >> 1) & 3;
  int offA[4], offB[4];
#pragma unroll
  for (int t = 0; t < 4; ++t) {
    offA[t] = (wm * 64 + t * 16 + fm) * 32 + ((fq ^ swz) * 8);
    offB[t] = (wn * 64 + t * 16 + fm) * 32 + ((fq ^ swz) * 8);
  }

  f32x4 acc[4][4];
  const f32x4 zero = {0.f, 0.f, 0.f, 0.f};
#pragma unroll
  for (int i = 0; i < 4; ++i)
#pragma unroll
    for (int j = 0; j < 4; ++j) acc[i][j] = zero;

  // segment order: scaled cross terms first (scale 2^12), exact pow2 rescale, then hi*hi
  const _Float16* Aseg[3] = { xlo, xhi, xhi };
  const _Float16* Bseg[3] = { whi, wlo, whi };

  for (int seg = 0; seg < 3; ++seg) {
    if (seg == 2) {
#pragma unroll
      for (int i = 0; i < 4; ++i)
#pragma unroll
        for (int j = 0; j < 4; ++j) acc[i][j] *= (1.0f / 4096.0f);
    }
    const _Float16* A = Aseg[seg] + (size_t)m0 * K_DIM;
    const _Float16* B = Bseg[seg] + (size_t)n0 * K_DIM;

    for (int kb = 0; kb < K_DIM; kb += 32) {
      __syncthreads();
#pragma unroll
      for (int j = 0; j < 2; ++j) {
        int row = j * 64 + srow;
        int g = sch ^ ((row >> 1) & 3);   // which global chunk lands in LDS slot sch
        GLDS(A + (size_t)row * K_DIM + kb + g * 8, &lA[row * 32 + sch * 8]);
        GLDS(B + (size_t)row * K_DIM + kb + g * 8, &lB[row * 32 + sch * 8]);
      }
      __builtin_amdgcn_s_waitcnt(0);
      __syncthreads();

      half8 af[4], bf[4];
#pragma unroll
      for (int t = 0; t < 4; ++t) af[t] = *(const half8*)&lA[offA[t]];
#pragma unroll
      for (int t = 0; t < 4; ++t) bf[t] = *(const half8*)&lB[offB[t]];
#pragma unroll
      for (int mt = 0; mt < 4; ++mt)
#pragma unroll
        for (int nt = 0; nt < 4; ++nt)
          acc[mt][nt] = __builtin_amdgcn_mfma_f32_16x16x32_f16(af[mt], bf[nt], acc[mt][nt], 0, 0, 0);
    }
  }

  // epilogue: C/D layout col=lane&15, row=(lane>>4)*4+r
  const int col = lane & 15;
  const int r4 = (lane >> 4) << 2;
#pragma unroll
  for (int nt = 0; nt < 4; ++nt) {
    int gc = n0 + wn * 64 + nt * 16 + col;
    float bias = b_enc[gc];
#pragma unroll
    for (int mt = 0; mt < 4; ++mt) {
#pragma unroll
      for (int r = 0; r < 4; ++r) {
        int gr = m0 + wm * 64 + mt * 16 + r4 + r;
        a1[(size_t)gr * N_DIM + gc] = acc[mt][nt][r] + bias;
      }
    }
  }
}

// ---------------- top-64 per row: bitwise radix select (atomic-free counting) ----
#define TK_THREADS 512
#define TK_PER 64   // 32768 / 512
__launch_bounds__(512)
__global__ void topk_kernel(const float* __restrict__ a1, int* __restrict__ tk_idx,
                            float* __restrict__ tk_val)
{
  const int row = blockIdx.x;
  const float* pr = a1 + (size_t)row * N_DIM;
  const int tid = threadIdx.x;

  unsigned u[TK_PER];
#pragma unroll
  for (int i = 0; i < TK_PER; ++i) {
    union { float f; unsigned b; } c;
    c.f = pr[i * TK_THREADS + tid];
    u[i] = (c.b & 0x80000000u) ? ~c.b : (c.b | 0x80000000u);  // order-preserving key
  }

  __shared__ int red[8];
  unsigned prefix = 0;
  int needed = TOPK;
  for (int bit = 31; bit >= 0; --bit) {
    unsigned want = (prefix >> bit) | 1u;
    int cnt = 0;
#pragma unroll
    for (int i = 0; i < TK_PER; ++i) cnt += ((u[i] >> bit) == want) ? 1 : 0;
    for (int off = 32; off > 0; off >>= 1) cnt += __shfl_down(cnt, off);
    if ((tid & 63) == 0) red[tid >> 6] = cnt;
    __syncthreads();
    int total = red[0] + red[1] + red[2] + red[3] + red[4] + red[5] + red[6] + red[7];
    __syncthreads();
    if (total >= needed) prefix |= (1u << bit);
    else needed -= total;
  }
  // prefix = key of 64th largest; take all strictly greater + `needed` equals.
  __shared__ int c_gt, c_tie;
  if (tid == 0) { c_gt = 0; c_tie = 0; }
  __syncthreads();
#pragma unroll
  for (int i = 0; i < TK_PER; ++i) {
    if (u[i] > prefix) {
      int p = atomicAdd(&c_gt, 1);
      union { unsigned b; float f; } c;
      c.b = (u[i] & 0x80000000u) ? (u[i] & 0x7fffffffu) : ~u[i];
      tk_idx[row * TOPK + p] = i * TK_THREADS + tid;
      tk_val[row * TOPK + p] = c.f;
    }
  }
  __syncthreads();
  int base = c_gt;
#pragma unroll
  for (int i = 0; i < TK_PER; ++i) {
    if (u[i] == prefix) {
      int t = atomicAdd(&c_tie, 1);
      if (t < needed) {
        union { unsigned b; float f; } c;
        c.b = (u[i] & 0x80000000u) ? (u[i] & 0x7fffffffu) : ~u[i];
        tk_idx[row * TOPK + base + t] = i * TK_THREADS + tid;
        tk_val[row * TOPK + base + t] = c.f;
      }
    }
  }
}

// ---------------- sparse tied-weight decode: z2 = sum val_j * W[idx_j,:] + b_dec --
// fp16-hi W is plenty accurate here (error ~3e-4 absmax vs 0.0487 threshold).
__launch_bounds__(256)
__global__ void decode_kernel(const _Float16* __restrict__ whi, const int* __restrict__ tk_idx,
                              const float* __restrict__ tk_val, const float* __restrict__ b_dec,
                              float* __restrict__ out)
{
  const int row = blockIdx.x, tid = threadIdx.x;
  __shared__ int   sidx[TOPK];
  __shared__ float sval[TOPK];
  if (tid < TOPK) { sidx[tid] = tk_idx[row * TOPK + tid]; sval[tid] = tk_val[row * TOPK + tid]; }
  __syncthreads();

  const int c0 = tid * 8;
  const int c1 = (tid + 256) * 8;
  float acc0[8], acc1[8];
#pragma unroll
  for (int e = 0; e < 8; ++e) { acc0[e] = b_dec[c0 + e]; acc1[e] = b_dec[c1 + e]; }

  for (int j = 0; j < TOPK; ++j) {
    const _Float16* wr = whi + (size_t)sidx[j] * K_DIM;
    half8 w0 = *(const half8*)(wr + c0);
    half8 w1 = *(const half8*)(wr + c1);
    float v = sval[j];
#pragma unroll
    for (int e = 0; e < 8; ++e) { acc0[e] += v * (float)w0[e]; acc1[e] += v * (float)w1[e]; }
  }
  float* po = out + (size_t)row * K_DIM;
#pragma unroll
  for (int e = 0; e < 8; ++e) { po[c0 + e] = acc0[e]; po[c1 + e] = acc1[e]; }
}

extern "C" void kernel_launch(void* const* d_in, const int* in_sizes, int n_in,
                              void* d_out, int out_size, void* d_ws, size_t ws_size,
                              hipStream_t stream) {
  const float* x     = (const float*)d_in[0];
  const float* W     = (const float*)d_in[1];
  const float* b_enc = (const float*)d_in[2];
  const float* b_dec = (const float*)d_in[3];
  // d_in[4] = k (fixed at 64 for this problem)

  // workspace carve (~1.15 GB)
  _Float16* x_hi = (_Float16*)d_ws;
  _Float16* x_lo = x_hi + (size_t)M_DIM * K_DIM;
  _Float16* w_hi = x_lo + (size_t)M_DIM * K_DIM;
  _Float16* w_lo = w_hi + (size_t)N_DIM * K_DIM;
  float*    a1   = (float*)(w_lo + (size_t)N_DIM * K_DIM);
  int*      tk_idx = (int*)(a1 + (size_t)M_DIM * N_DIM);
  float*    tk_val = (float*)(tk_idx + M_DIM * TOPK);

  split_kernel<<<4096, 256, 0, stream>>>((const float4*)x, (half4*)x_hi, (half4*)x_lo,
                                         (int)((size_t)M_DIM * K_DIM / 4));
  split_kernel<<<8192, 256, 0, stream>>>((const float4*)W, (half4*)w_hi, (half4*)w_lo,
                                         (int)((size_t)N_DIM * K_DIM / 4));
  gemm_enc<<<(M_DIM / 128) * (N_DIM / 128), 256, 0, stream>>>(x_hi, x_lo, w_hi, w_lo, b_enc, a1);
  topk_kernel<<<M_DIM, TK_THREADS, 0, stream>>>(a1, tk_idx, tk_val);
  decode_kernel<<<M_DIM, 256, 0, stream>>>(w_hi, tk_idx, tk_val, b_dec, (float*)d_out);
}

// Round 2
// 4206.888 us; speedup vs baseline: 1.5141x; 1.5141x over previous
//
#include <hip/hip_runtime.h>

#define M_DIM 4096
#define K_DIM 4096
#define N_DIM 32768
#define TOPK  64
#define NCAND 96

typedef __attribute__((ext_vector_type(8))) _Float16 half8;
typedef __attribute__((ext_vector_type(4))) _Float16 half4;
typedef __attribute__((ext_vector_type(4))) float    f32x4;

#define GLDS(gp, lp) __builtin_amdgcn_global_load_lds( \
    (const __attribute__((address_space(1))) void*)(gp), \
    (__attribute__((address_space(3))) void*)(lp), 16, 0, 0)

// ---------------- cast: fp32 -> fp16 (hi only; phase-2 restores precision) -------
__launch_bounds__(256)
__global__ void cast_kernel(const float4* __restrict__ src, half4* __restrict__ dst, int n4) {
  int i = blockIdx.x * blockDim.x + threadIdx.x;
  int stride = gridDim.x * blockDim.x;
  for (; i < n4; i += stride) {
    float4 x = src[i];
    half4 h;
    h[0] = (_Float16)x.x; h[1] = (_Float16)x.y; h[2] = (_Float16)x.z; h[3] = (_Float16)x.w;
    dst[i] = h;
  }
}

// ---------------- encode GEMM (fp16 approx): a1 = x_h @ W_h^T + b_enc -----------
// m97 structure: 128x128 tile, BK=32, 4 waves of 64x64, 16x16x32 f16 MFMA,
// global_load_lds width 16, XOR chunk swizzle for conflict-free ds_read_b128.
__launch_bounds__(256)
__global__ void gemm_enc(const _Float16* __restrict__ xh, const _Float16* __restrict__ wh,
                         const float* __restrict__ b_enc, float* __restrict__ a1)
{
  __shared__ alignas(16) _Float16 lA[128 * 32];
  __shared__ alignas(16) _Float16 lB[128 * 32];

  const int tid  = threadIdx.x;
  const int lane = tid & 63;
  const int wave = tid >> 6;
  const int wm = wave & 1, wn = wave >> 1;

  // window swizzle: 32 windows of (32 m-tiles x 8 n-tiles) -> A stays L3-hot.
  const int bid = blockIdx.x;
  const int window = bid >> 8;
  const int within = bid & 255;
  const int m0 = (within & 31) << 7;
  const int n0 = (((window << 3) | (within >> 5))) << 7;

  const int srow = tid >> 2;
  const int sch  = tid & 3;

  const int fm = lane & 15, fq = lane >> 4;
  const int swz = (fm >> 1) & 3;
  int offA[4], offB[4];
#pragma unroll
  for (int t = 0; t < 4; ++t) {
    offA[t] = (wm * 64 + t * 16 + fm) * 32 + ((fq ^ swz) * 8);
    offB[t] = (wn * 64 + t * 16 + fm) * 32 + ((fq ^ swz) * 8);
  }

  f32x4 acc[4][4];
  const f32x4 zero = {0.f, 0.f, 0.f, 0.f};
#pragma unroll
  for (int i = 0; i < 4; ++i)
#pragma unroll
    for (int j = 0; j < 4; ++j) acc[i][j] = zero;

  const _Float16* A = xh + (size_t)m0 * K_DIM;
  const _Float16* B = wh + (size_t)n0 * K_DIM;

  for (int kb = 0; kb < K_DIM; kb += 32) {
    __syncthreads();
#pragma unroll
    for (int j = 0; j < 2; ++j) {
      int row = j * 64 + srow;
      int g = sch ^ ((row >> 1) & 3);
      GLDS(A + (size_t)row * K_DIM + kb + g * 8, &lA[row * 32 + sch * 8]);
      GLDS(B + (size_t)row * K_DIM + kb + g * 8, &lB[row * 32 + sch * 8]);
    }
    __builtin_amdgcn_s_waitcnt(0);
    __syncthreads();

    half8 af[4], bf[4];
#pragma unroll
    for (int t = 0; t < 4; ++t) af[t] = *(const half8*)&lA[offA[t]];
#pragma unroll
    for (int t = 0; t < 4; ++t) bf[t] = *(const half8*)&lB[offB[t]];
#pragma unroll
    for (int mt = 0; mt < 4; ++mt)
#pragma unroll
      for (int nt = 0; nt < 4; ++nt)
        acc[mt][nt] = __builtin_amdgcn_mfma_f32_16x16x32_f16(af[mt], bf[nt], acc[mt][nt], 0, 0, 0);
  }

  const int col = lane & 15;
  const int r4 = (lane >> 4) << 2;
#pragma unroll
  for (int nt = 0; nt < 4; ++nt) {
    int gc = n0 + wn * 64 + nt * 16 + col;
    float bias = b_enc[gc];
#pragma unroll
    for (int mt = 0; mt < 4; ++mt) {
#pragma unroll
      for (int r = 0; r < 4; ++r) {
        int gr = m0 + wm * 64 + mt * 16 + r4 + r;
        a1[(size_t)gr * N_DIM + gc] = acc[mt][nt][r] + bias;
      }
    }
  }
}

// ---------------- top-96 per row on fp16-approx acts: bitwise radix select -------
#define TK_THREADS 512
#define TK_PER 64   // 32768 / 512
__launch_bounds__(512)
__global__ void topk_kernel(const float* __restrict__ a1, int* __restrict__ cand)
{
  const int row = blockIdx.x;
  const float* pr = a1 + (size_t)row * N_DIM;
  const int tid = threadIdx.x;

  unsigned u[TK_PER];
#pragma unroll
  for (int i = 0; i < TK_PER; ++i) {
    union { float f; unsigned b; } c;
    c.f = pr[i * TK_THREADS + tid];
    u[i] = (c.b & 0x80000000u) ? ~c.b : (c.b | 0x80000000u);  // order-preserving key
  }

  __shared__ int red[8];
  unsigned prefix = 0;
  int needed = NCAND;
  for (int bit = 31; bit >= 0; --bit) {
    unsigned want = (prefix >> bit) | 1u;
    int cnt = 0;
#pragma unroll
    for (int i = 0; i < TK_PER; ++i) cnt += ((u[i] >> bit) == want) ? 1 : 0;
    for (int off = 32; off > 0; off >>= 1) cnt += __shfl_down(cnt, off);
    if ((tid & 63) == 0) red[tid >> 6] = cnt;
    __syncthreads();
    int total = red[0] + red[1] + red[2] + red[3] + red[4] + red[5] + red[6] + red[7];
    __syncthreads();
    if (total >= needed) prefix |= (1u << bit);
    else needed -= total;
  }
  __shared__ int c_gt, c_tie;
  if (tid == 0) { c_gt = 0; c_tie = 0; }
  __syncthreads();
#pragma unroll
  for (int i = 0; i < TK_PER; ++i) {
    if (u[i] > prefix) {
      int p = atomicAdd(&c_gt, 1);
      cand[row * NCAND + p] = i * TK_THREADS + tid;
    }
  }
  __syncthreads();
  int base = c_gt;
#pragma unroll
  for (int i = 0; i < TK_PER; ++i) {
    if (u[i] == prefix) {
      int t = atomicAdd(&c_tie, 1);
      if (t < needed) cand[row * NCAND + base + t] = i * TK_THREADS + tid;
    }
  }
}

// ---------------- refine: exact fp32 acts for 96 cands, exact top-64 ------------
// one block per row; each wave holds full x row in regs (64 float4/lane layout
// matched to coalesced W-row reads), processes cands round-robin.
__launch_bounds__(256)
__global__ void refine_kernel(const float* __restrict__ x, const float* __restrict__ W,
                              const float* __restrict__ b_enc, const int* __restrict__ cand,
                              int* __restrict__ tk_idx, float* __restrict__ tk_val)
{
  const int row = blockIdx.x;
  const int tid = threadIdx.x, lane = tid & 63, wave = tid >> 6;
  __shared__ float svals[NCAND];
  __shared__ int   sidx[NCAND];
  __shared__ int   spos;

  const float* xr = x + (size_t)row * K_DIM;
  float4 xv[16];
#pragma unroll
  for (int c = 0; c < 16; ++c) xv[c] = *(const float4*)(xr + c * 256 + lane * 4);

  for (int j = wave; j < NCAND; j += 4) {
    int cj = cand[row * NCAND + j];
    const float* wr = W + (size_t)cj * K_DIM;
    float acc = 0.f;
#pragma unroll
    for (int c = 0; c < 16; ++c) {
      float4 wv = *(const float4*)(wr + c * 256 + lane * 4);
      acc += xv[c].x * wv.x + xv[c].y * wv.y + xv[c].z * wv.z + xv[c].w * wv.w;
    }
#pragma unroll
    for (int off = 32; off > 0; off >>= 1) acc += __shfl_down(acc, off, 64);
    if (lane == 0) { svals[j] = acc + b_enc[cj]; sidx[j] = cj; }
  }
  if (tid == 0) spos = 0;
  __syncthreads();

  if (tid < NCAND) {
    float v = svals[tid];
    int myidx = sidx[tid];
    int rank = 0;
    for (int i = 0; i < NCAND; ++i) {
      float vi = svals[i];
      rank += (vi > v || (vi == v && sidx[i] < myidx)) ? 1 : 0;  // lax.top_k tie-break
    }
    if (rank < TOPK) {
      int p = atomicAdd(&spos, 1);
      tk_idx[row * TOPK + p] = myidx;
      tk_val[row * TOPK + p] = v;
    }
  }
}

// ---------------- sparse tied-weight decode: z2 = sum val_j * W[idx_j,:] + b_dec --
__launch_bounds__(256)
__global__ void decode_kernel(const _Float16* __restrict__ wh, const int* __restrict__ tk_idx,
                              const float* __restrict__ tk_val, const float* __restrict__ b_dec,
                              float* __restrict__ out)
{
  const int row = blockIdx.x, tid = threadIdx.x;
  __shared__ int   sidx[TOPK];
  __shared__ float sval[TOPK];
  if (tid < TOPK) { sidx[tid] = tk_idx[row * TOPK + tid]; sval[tid] = tk_val[row * TOPK + tid]; }
  __syncthreads();

  const int c0 = tid * 8;
  const int c1 = (tid + 256) * 8;
  float acc0[8], acc1[8];
#pragma unroll
  for (int e = 0; e < 8; ++e) { acc0[e] = b_dec[c0 + e]; acc1[e] = b_dec[c1 + e]; }

  for (int j = 0; j < TOPK; ++j) {
    const _Float16* wr = wh + (size_t)sidx[j] * K_DIM;
    half8 w0 = *(const half8*)(wr + c0);
    half8 w1 = *(const half8*)(wr + c1);
    float v = sval[j];
#pragma unroll
    for (int e = 0; e < 8; ++e) { acc0[e] += v * (float)w0[e]; acc1[e] += v * (float)w1[e]; }
  }
  float* po = out + (size_t)row * K_DIM;
#pragma unroll
  for (int e = 0; e < 8; ++e) { po[c0 + e] = acc0[e]; po[c1 + e] = acc1[e]; }
}

extern "C" void kernel_launch(void* const* d_in, const int* in_sizes, int n_in,
                              void* d_out, int out_size, void* d_ws, size_t ws_size,
                              hipStream_t stream) {
  const float* x     = (const float*)d_in[0];
  const float* W     = (const float*)d_in[1];
  const float* b_enc = (const float*)d_in[2];
  const float* b_dec = (const float*)d_in[3];

  // workspace carve (~840 MB)
  _Float16* x_h = (_Float16*)d_ws;
  _Float16* w_h = x_h + (size_t)M_DIM * K_DIM;
  float*    a1  = (float*)(w_h + (size_t)N_DIM * K_DIM);
  int*      cand = (int*)(a1 + (size_t)M_DIM * N_DIM);
  int*      tk_idx = cand + (size_t)M_DIM * NCAND;
  float*    tk_val = (float*)(tk_idx + M_DIM * TOPK);

  cast_kernel<<<4096, 256, 0, stream>>>((const float4*)x, (half4*)x_h,
                                        (int)((size_t)M_DIM * K_DIM / 4));
  cast_kernel<<<8192, 256, 0, stream>>>((const float4*)W, (half4*)w_h,
                                        (int)((size_t)N_DIM * K_DIM / 4));
  gemm_enc<<<(M_DIM / 128) * (N_DIM / 128), 256, 0, stream>>>(x_h, w_h, b_enc, a1);
  topk_kernel<<<M_DIM, TK_THREADS, 0, stream>>>(a1, cand);
  refine_kernel<<<M_DIM, 256, 0, stream>>>(x, W, b_enc, cand, tk_idx, tk_val);
  decode_kernel<<<M_DIM, 256, 0, stream>>>(w_h, tk_idx, tk_val, b_dec, (float*)d_out);
}